// Round 7
// baseline (586.108 us; speedup 1.0000x reference)
//
#include <hip/hip_runtime.h>

// LSTM-GCN single step from (H=0, C=0).
// Collapsed math: Fg gate dead (C_prev=0), cheb(H,..)=bh, peephole wc[0],wc[1] dead.
//
// R7: R6 counters showed gather's wall = L2 fill from random x rows
// (FETCH 149 MB = 73% miss of 205 MB logical, matching 12.8MB-vs-4MiB-L2).
// -> prescaled x rows stored as bf16 (6.4 MB working set, 64-B rows),
//    xscale fused into deg, sort tiles halved for 2x sort parallelism.
// No global atomics anywhere; only LDS atomics.

#define FDIM 32
#define MAX_N 100000
#define MAX_E 1600000
#define TILE 4096            // edges per sort tile (256 thr x 16)
#define NB_MAXB 3136         // max 32-node buckets (100000/32 -> 3125)
#define NBLK_MAX 400         // 1.6M / 4096 = 391
#define SCAN_TILE 8192       // scan1/scan3: 1024 thr x 8

__device__ float          g_dinv[MAX_N];
__device__ unsigned short g_xs[MAX_N * FDIM];     // bf16 bits of dinv[node]*x[node]
__device__ int   g_tileh[2 * NB_MAXB * NBLK_MAX]; // [src bins | dst bins] x tile, bin-major
__device__ int   g_blk[1024];
__device__ int   g_total;                         // 2 * (valid edge count)
__device__ uint2 g_rec[2 * MAX_E];                // [src-sorted | dst-sorted] records
__device__ float g_tx1[MAX_N * FDIM];             // L_hat @ x

// ---- per-tile dual histogram (bin-major output) -----------------------------
__global__ __launch_bounds__(256) void count_kernel(const int* __restrict__ ei,
                                                    int E, int n_nodes, int nblk,
                                                    int NB) {
    __shared__ int hist[2 * NB_MAXB];           // 25 KB
    int nb2 = 2 * NB;
    for (int i = threadIdx.x; i < nb2; i += 256) hist[i] = 0;
    __syncthreads();
    int base = blockIdx.x * TILE;
    int lim  = min(TILE, E - base);
    for (int t = threadIdx.x; t < lim; t += 256) {
        int e = base + t;
        int s = ei[e], d = ei[E + e];
        if ((unsigned)s >= (unsigned)n_nodes || (unsigned)d >= (unsigned)n_nodes) continue;
        atomicAdd(&hist[s >> 5], 1);
        atomicAdd(&hist[NB + (d >> 5)], 1);
    }
    __syncthreads();
    for (int i = threadIdx.x; i < nb2; i += 256)
        g_tileh[i * nblk + blockIdx.x] = hist[i];
}

// ---- exclusive scan over g_tileh[0..n): 1024-thr blocks, 8 elems/thread -----
__global__ __launch_bounds__(1024) void scan1_kernel(int n) {
    __shared__ int sh[1024];
    int tid = threadIdx.x;
    int base = blockIdx.x * SCAN_TILE + tid * 8;
    int v[8];
#pragma unroll
    for (int i = 0; i < 8; ++i) v[i] = (base + i < n) ? g_tileh[base + i] : 0;
    int tsum = 0;
#pragma unroll
    for (int i = 0; i < 8; ++i) tsum += v[i];
    sh[tid] = tsum;
    __syncthreads();
    for (int off = 1; off < 1024; off <<= 1) {
        int t = (tid >= off) ? sh[tid - off] : 0;
        __syncthreads();
        sh[tid] += t;
        __syncthreads();
    }
    if (tid == 1023) g_blk[blockIdx.x] = sh[1023];
    int run = sh[tid] - tsum;
#pragma unroll
    for (int i = 0; i < 8; ++i) {
        if (base + i < n) g_tileh[base + i] = run;
        run += v[i];
    }
}

__global__ __launch_bounds__(256) void scan2_kernel(int nb) {   // nb <= 1024
    __shared__ int sh[256];
    int tid = threadIdx.x;
    int base = tid * 4;
    int v[4];
#pragma unroll
    for (int i = 0; i < 4; ++i) v[i] = (base + i < nb) ? g_blk[base + i] : 0;
    int tsum = v[0] + v[1] + v[2] + v[3];
    sh[tid] = tsum;
    __syncthreads();
    for (int off = 1; off < 256; off <<= 1) {
        int t = (tid >= off) ? sh[tid - off] : 0;
        __syncthreads();
        sh[tid] += t;
        __syncthreads();
    }
    if (tid == 255) g_total = sh[255];          // grand total = 2 * valid edges
    int run = sh[tid] - tsum;
#pragma unroll
    for (int i = 0; i < 4; ++i) {
        if (base + i < nb) g_blk[base + i] = run;
        run += v[i];
    }
}

__global__ __launch_bounds__(1024) void scan3_kernel(int n) {
    int off = g_blk[blockIdx.x];
    int base = blockIdx.x * SCAN_TILE + threadIdx.x * 8;
#pragma unroll
    for (int i = 0; i < 8; ++i)
        if (base + i < n) g_tileh[base + i] += off;
}

// ---- scatter both sorts with LDS cursors (no global atomics) ----------------
__global__ __launch_bounds__(256) void scatter_kernel(const int* __restrict__ ei,
                                                      const float* __restrict__ w,
                                                      int E, int n_nodes, int nblk,
                                                      int NB) {
    __shared__ int cur[2 * NB_MAXB];            // 25 KB
    int nb2 = 2 * NB;
    for (int i = threadIdx.x; i < nb2; i += 256)
        cur[i] = g_tileh[i * nblk + blockIdx.x];
    __syncthreads();
    int base = blockIdx.x * TILE;
    int lim  = min(TILE, E - base);
    for (int t = threadIdx.x; t < lim; t += 256) {
        int e = base + t;
        int s = ei[e], d = ei[E + e];
        if ((unsigned)s >= (unsigned)n_nodes || (unsigned)d >= (unsigned)n_nodes) continue;
        unsigned wb = __float_as_uint((s == d) ? 0.f : w[e]);
        int pa = atomicAdd(&cur[s >> 5], 1);            // LDS atomic
        g_rec[pa] = make_uint2((unsigned)(s & 31), wb);
        int pb = atomicAdd(&cur[NB + (d >> 5)], 1);     // LDS atomic
        g_rec[pb] = make_uint2((unsigned)s | ((unsigned)(d & 31) << 17), wb);
    }
}

// ---- per-bucket degree + rsqrt + fused bf16 row prescale --------------------
__global__ __launch_bounds__(256) void deg_kernel(const float* __restrict__ x,
                                                  int n_nodes, int nblk, int NB) {
    __shared__ float degl[32];
    __shared__ float dinvl[32];
    int bin = blockIdx.x, tid = threadIdx.x;
    if (tid < 32) degl[tid] = 0.f;
    __syncthreads();
    int start = g_tileh[bin * nblk];
    int end   = (bin + 1 < NB) ? g_tileh[(bin + 1) * nblk] : g_tileh[NB * nblk];
    for (int i = start + tid; i < end; i += 256) {
        uint2 r = g_rec[i];
        atomicAdd(&degl[r.x & 31], __uint_as_float(r.y));   // LDS atomic
    }
    __syncthreads();
    if (tid < 32) {
        int node = bin * 32 + tid;
        float dg = degl[tid];
        float dv = (dg > 0.f) ? rsqrtf(dg) : 0.f;
        dinvl[tid] = dv;
        if (node < n_nodes) g_dinv[node] = dv;
    }
    __syncthreads();
    int nodeb = bin * 32;
    for (int j = tid; j < 32 * FDIM; j += 256) {      // xs = bf16(dinv * x)
        int node = nodeb + (j >> 5);
        if (node < n_nodes) {
            float v = x[node * FDIM + (j & 31)] * dinvl[j >> 5];
            unsigned b = __float_as_uint(v);
            unsigned rb = (b + 0x7FFFu + ((b >> 16) & 1u)) >> 16;   // RNE
            g_xs[node * FDIM + (j & 31)] = (unsigned short)rb;
        }
    }
}

// ---- per-bucket gather: tx1 = L_hat @ x (dst-sorted section, bf16 rows) -----
__global__ __launch_bounds__(256) void gather_kernel(int n_nodes, int nblk, int NB) {
    __shared__ float acc[32 * FDIM];    // 4 KB
    __shared__ float dneg[32];
    int tid = threadIdx.x, bin = blockIdx.x;
    for (int i = tid; i < 32 * FDIM; i += 256) acc[i] = 0.f;
    if (tid < 32) {
        int node = bin * 32 + tid;
        dneg[tid] = (node < n_nodes) ? -g_dinv[node] : 0.f;
    }
    __syncthreads();
    int start = g_tileh[(NB + bin) * nblk];
    int end   = (bin + 1 < NB) ? g_tileh[(NB + bin + 1) * nblk] : g_total;
    int hw = tid >> 5, f = tid & 31;
    int i = start + hw;
    for (; i + 56 < end; i += 64) {     // 8 half-waves x unroll-8
        uint2 r[8];
#pragma unroll
        for (int j = 0; j < 8; ++j) r[j] = g_rec[i + 8 * j];
        float xv[8];
#pragma unroll
        for (int j = 0; j < 8; ++j) {
            unsigned short u = g_xs[(r[j].x & 0x1FFFF) * FDIM + f];
            xv[j] = __uint_as_float(((unsigned)u) << 16);
        }
#pragma unroll
        for (int j = 0; j < 8; ++j) {
            int dl = r[j].x >> 17;
            atomicAdd(&acc[dl * FDIM + f],
                      dneg[dl] * __uint_as_float(r[j].y) * xv[j]);   // LDS atomic
        }
    }
    for (; i < end; i += 8) {
        uint2 r = g_rec[i];
        int dl = r.x >> 17;
        unsigned short u = g_xs[(r.x & 0x1FFFF) * FDIM + f];
        atomicAdd(&acc[dl * FDIM + f],
                  dneg[dl] * __uint_as_float(r.y) * __uint_as_float(((unsigned)u) << 16));
    }
    __syncthreads();
    int nodeb = bin * 32;
    for (int j = tid; j < 32 * FDIM; j += 256) {
        int node = nodeb + (j >> 5);
        if (node < n_nodes) g_tx1[node * FDIM + (j & 31)] = acc[j];
    }
}

// ---- gates + epilogue (unchanged; correctness-proven) -----------------------
__global__ __launch_bounds__(256) void gates_kernel(
    const float* __restrict__ x,
    const float* __restrict__ Wx, const float* __restrict__ bx,
    const float* __restrict__ bh, const float* __restrict__ wc,
    const float* __restrict__ bg, const float* __restrict__ lin_w,
    const float* __restrict__ lin_b, float* __restrict__ out, int n_nodes) {
    __shared__ float Ws[3 * 2048];      // gates {i,c,o} x K=2 x 32x32
    __shared__ float xs[8 * FDIM];
    __shared__ float ts[8 * FDIM];

    for (int idx = threadIdx.x; idx < 2048; idx += 256) {
        Ws[idx]          = Wx[0 * 2048 + idx];
        Ws[2048 + idx]   = Wx[2 * 2048 + idx];
        Ws[4096 + idx]   = Wx[3 * 2048 + idx];
    }
    int node0 = blockIdx.x * 8;
    {
        int n = node0 + (threadIdx.x >> 5);
        int f = threadIdx.x & 31;
        if (n < n_nodes) {
            xs[threadIdx.x] = x[n * FDIM + f];
            ts[threadIdx.x] = g_tx1[n * FDIM + f];
        }
    }
    __syncthreads();

    int ln = threadIdx.x >> 5;
    int j  = threadIdx.x & 31;
    int n  = node0 + ln;
    if (n >= n_nodes) return;

    const float* xr = &xs[ln * FDIM];
    const float* tr = &ts[ln * FDIM];
    float acc_i = 0.f, acc_c = 0.f, acc_o = 0.f;
#pragma unroll
    for (int k = 0; k < 32; ++k) {
        float xv = xr[k], tv = tr[k];
        int o0 = k * 32 + j;
        acc_i += xv * Ws[o0]          + tv * Ws[1024 + o0];
        acc_c += xv * Ws[2048 + o0]   + tv * Ws[3072 + o0];
        acc_o += xv * Ws[4096 + o0]   + tv * Ws[5120 + o0];
    }
    float bi = bx[0 * 32 + j] + bh[0 * 32 + j] + bg[0 * 32 + j];
    float bc = bx[2 * 32 + j] + bh[2 * 32 + j] + bg[2 * 32 + j];
    float bo = bx[3 * 32 + j] + bh[3 * 32 + j] + bg[3 * 32 + j];

    float I = 1.f / (1.f + __expf(-(acc_i + bi)));
    float T = tanhf(acc_c + bc);
    float C = I * T;                                    // Fg*C_prev = 0
    float O = 1.f / (1.f + __expf(-(acc_o + bo + wc[2 * 32 + j] * C)));
    float H = O * tanhf(C);
    float r = fmaxf(H, 0.f) * lin_w[j];
#pragma unroll
    for (int m = 16; m > 0; m >>= 1) r += __shfl_xor(r, m, 32);
    if (j == 0) out[n] = r + lin_b[0];
}

extern "C" void kernel_launch(void* const* d_in, const int* in_sizes, int n_in,
                              void* d_out, int out_size, void* d_ws, size_t ws_size,
                              hipStream_t stream) {
    const float* x     = (const float*)d_in[0];
    const int*   ei    = (const int*)d_in[1];      // int32 on device
    const float* w     = (const float*)d_in[2];
    const float* Wx    = (const float*)d_in[3];
    const float* bx    = (const float*)d_in[4];
    // d_in[5] = Wh: unused (H=0)
    const float* bh    = (const float*)d_in[6];
    const float* wc    = (const float*)d_in[7];
    const float* bg    = (const float*)d_in[8];
    const float* lin_w = (const float*)d_in[9];
    const float* lin_b = (const float*)d_in[10];
    float*       out   = (float*)d_out;

    int n_nodes = in_sizes[0] / FDIM;
    if (n_nodes > MAX_N) n_nodes = MAX_N;
    int E = in_sizes[2];
    if (E > MAX_E) E = MAX_E;

    const int nblk = (E + TILE - 1) / TILE;          // 391
    const int NB   = (n_nodes + 31) >> 5;            // 3125
    const int n_scan = 2 * NB * nblk;                // 2.44M
    const int sb   = (n_scan + SCAN_TILE - 1) / SCAN_TILE;   // 299 (<=1024)

    count_kernel<<<nblk, 256, 0, stream>>>(ei, E, n_nodes, nblk, NB);
    scan1_kernel<<<sb, 1024, 0, stream>>>(n_scan);
    scan2_kernel<<<1, 256, 0, stream>>>(sb);
    scan3_kernel<<<sb, 1024, 0, stream>>>(n_scan);
    scatter_kernel<<<nblk, 256, 0, stream>>>(ei, w, E, n_nodes, nblk, NB);
    deg_kernel<<<NB, 256, 0, stream>>>(x, n_nodes, nblk, NB);
    gather_kernel<<<NB, 256, 0, stream>>>(n_nodes, nblk, NB);
    gates_kernel<<<(n_nodes + 7) / 8, 256, 0, stream>>>(
        x, Wx, bx, bh, wc, bg, lin_w, lin_b, out, n_nodes);
}